// Round 7
// baseline (86.580 us; speedup 1.0000x reference)
//
#include <hip/hip_runtime.h>
#include <hip/hip_bf16.h>
#include <math.h>

// ---------------------------------------------------------------------------
// HybridQuantumLinear, single dispatch.
//   Blocks 0..31 additionally build U (256x256 fixed unitary) -> Bt[512][256]
//   bf16 in d_ws (row n = 2i+c re/im of output amp i, col j = input amp),
//   then release per-block markers (device-scope).
//   All 256 blocks (32 batch rows each):
//     G1: enc_pre = x @ W_in^T via MFMA with hi/lo bf16 split (K=1024) —
//         waves 0,1 only; C fragments -> tanh -> (cos,sin) per (row,qubit).
//     psi assembly: 512 threads build the 256-amp REAL product state by
//         outer-product tree -> XOR-swizzled LDS (bf16).
//     spin on markers (acquire) until U complete; self-cleaning done-counter.
//     G2: psi_out = psi @ Bt^T via MFMA (K=256, N=512), wave -> 64 cols.
//     epilogue: P=re^2+im^2 ; z_q = sum sign_q(i) P ; out = z @ W_out^T.
// Amp index i: bit(7-q) = qubit q.
// ---------------------------------------------------------------------------

typedef __attribute__((ext_vector_type(8))) short bf16x8;
typedef __attribute__((ext_vector_type(4))) float f32x4;

#define MAGIC 0x13572468u

static __device__ __forceinline__ unsigned short f2bf(float f) {
  __hip_bfloat16 h = __float2bfloat16(f);
  return *reinterpret_cast<unsigned short*>(&h);
}
static __device__ __forceinline__ float bf2f(unsigned short u) {
  unsigned int v = ((unsigned int)u) << 16;
  float r;
  __builtin_memcpy(&r, &v, 4);
  return r;
}

__device__ __forceinline__ float2 shfl_xor_f2(float2 v, int m) {
  float2 r;
  r.x = __shfl_xor(v.x, m, 64);
  r.y = __shfl_xor(v.y, m, 64);
  return r;
}
__device__ __forceinline__ float2 cfma(float2 u, float2 v, float2 acc) {
  acc.x = fmaf(u.x, v.x, fmaf(-u.y, v.y, acc.x));
  acc.y = fmaf(u.x, v.y, fmaf(u.y, v.x, acc.y));
  return acc;
}

__device__ __forceinline__ void apply_gate(float2 (&a)[4], int q, float2 u00,
                                           float2 u01, float2 u10, float2 u11,
                                           int lane) {
  const float2 z0 = make_float2(0.f, 0.f);
  if (q == 7) {
    float2 n0 = cfma(u00, a[0], cfma(u01, a[1], z0));
    float2 n1 = cfma(u10, a[0], cfma(u11, a[1], z0));
    float2 n2 = cfma(u00, a[2], cfma(u01, a[3], z0));
    float2 n3 = cfma(u10, a[2], cfma(u11, a[3], z0));
    a[0] = n0; a[1] = n1; a[2] = n2; a[3] = n3;
  } else if (q == 6) {
    float2 n0 = cfma(u00, a[0], cfma(u01, a[2], z0));
    float2 n2 = cfma(u10, a[0], cfma(u11, a[2], z0));
    float2 n1 = cfma(u00, a[1], cfma(u01, a[3], z0));
    float2 n3 = cfma(u10, a[1], cfma(u11, a[3], z0));
    a[0] = n0; a[1] = n1; a[2] = n2; a[3] = n3;
  } else {
    int m = 1 << (5 - q);
    bool b = (lane >> (5 - q)) & 1;
    float2 ca = b ? u11 : u00;
    float2 cp = b ? u10 : u01;
    #pragma unroll
    for (int k = 0; k < 4; ++k) {
      float2 p = shfl_xor_f2(a[k], m);
      a[k] = cfma(ca, a[k], cfma(cp, p, z0));
    }
  }
}

__device__ __forceinline__ void apply_cnot(float2 (&a)[4], int q, int lane) {
  if (q <= 4) {
    int m = 1 << (4 - q);
    bool ctrl = (lane >> (5 - q)) & 1;
    #pragma unroll
    for (int k = 0; k < 4; ++k) {
      float2 p = shfl_xor_f2(a[k], m);
      a[k].x = ctrl ? p.x : a[k].x;
      a[k].y = ctrl ? p.y : a[k].y;
    }
  } else if (q == 5) {
    bool ct = lane & 1;
    float2 n0 = ct ? a[2] : a[0];
    float2 n1 = ct ? a[3] : a[1];
    float2 n2 = ct ? a[0] : a[2];
    float2 n3 = ct ? a[1] : a[3];
    a[0] = n0; a[1] = n1; a[2] = n2; a[3] = n3;
  } else {
    float2 t = a[2]; a[2] = a[3]; a[3] = t;
  }
}

__global__ __launch_bounds__(512, 1) void mono_kernel(
    const float* __restrict__ x, const float* __restrict__ W_in,
    const float* __restrict__ W_out, const float* __restrict__ theta,
    __hip_bfloat16* __restrict__ Bt, unsigned* __restrict__ ctrl,
    float* __restrict__ out) {
  __shared__ float mats[256];          // 32 fused gate matrices
  __shared__ char Wlds[32768];         // W_in hi/lo bf16 [16][1024], swizzled
  __shared__ float2 cs_lds[32][8];     // (cos,sin) per (row, qubit)
  __shared__ char psi_lds[16384];      // 32 x 256 bf16, XOR-swizzled
  __shared__ float z_lds[8][32][8];
  __shared__ float z_final[32][8];

  const int tid = threadIdx.x;
  const int lane = tid & 63;
  const int w = tid >> 6;
  const int cl = lane & 15;
  const int kg = lane >> 4;
  const int bid = blockIdx.x;
  const int rowbase = bid * 32;

  // ================ U-build (blocks 0..31; 8 waves = 8 basis cols) =========
  if (bid < 32) {
    if (tid < 32) {  // fuse RZ*RY*RX per (layer, qubit)
      int l = tid >> 3, q = tid & 7;
      const float* th = theta + (l * 8 + q) * 3;
      float h1 = 0.5f * th[0], h2 = 0.5f * th[1], h3 = 0.5f * th[2];
      float c1 = cosf(h1), s1 = sinf(h1);
      float c2 = cosf(h2), s2 = sinf(h2);
      float c3 = cosf(h3), s3 = sinf(h3);
      float m00r = c2 * c1, m00i = s2 * s1;
      float m01r = -s2 * c1, m01i = -c2 * s1;
      float m10r = s2 * c1, m10i = -c2 * s1;
      float m11r = c1 * c2, m11i = -s1 * s2;
      float* o = &mats[tid * 8];
      o[0] = c3 * m00r + s3 * m00i;  o[1] = c3 * m00i - s3 * m00r;
      o[2] = c3 * m01r + s3 * m01i;  o[3] = c3 * m01i - s3 * m01r;
      o[4] = c3 * m10r - s3 * m10i;  o[5] = c3 * m10i + s3 * m10r;
      o[6] = c3 * m11r - s3 * m11i;  o[7] = c3 * m11i + s3 * m11r;
    }
    __syncthreads();

    const int j = bid * 8 + w;  // basis column 0..255
    float2 a[4];
    #pragma unroll
    for (int k = 0; k < 4; ++k)
      a[k] = make_float2((lane * 4 + k == j) ? 1.f : 0.f, 0.f);

    #pragma unroll
    for (int l = 0; l < 4; ++l) {
      #pragma unroll
      for (int q = 0; q < 8; ++q) {
        const float* m = &mats[(l * 8 + q) * 8];
        apply_gate(a, q, make_float2(m[0], m[1]), make_float2(m[2], m[3]),
                   make_float2(m[4], m[5]), make_float2(m[6], m[7]), lane);
      }
      #pragma unroll
      for (int i = (l & 1); i < 7; i += 2) apply_cnot(a, i, lane);
    }
    #pragma unroll
    for (int k = 0; k < 4; ++k) {
      int n0 = (lane * 4 + k) * 2;
      Bt[n0 * 256 + j]       = __float2bfloat16(a[k].x);
      Bt[(n0 + 1) * 256 + j] = __float2bfloat16(a[k].y);
    }
    __syncthreads();
    if (tid == 0) {
      __threadfence();
      __hip_atomic_store(&ctrl[bid], MAGIC, __ATOMIC_RELEASE,
                         __HIP_MEMORY_SCOPE_AGENT);
    }
  }

  // ================ stage W_in hi/lo into Wlds (rows 8..15 zero) ===========
  {
    const int q = tid >> 6;    // 0..7
    const int ch = tid & 63;   // 8 floats each
    float4 wa = *(const float4*)(W_in + q * 512 + ch * 8);
    float4 wb = *(const float4*)(W_in + q * 512 + ch * 8 + 4);
    float f[8] = {wa.x, wa.y, wa.z, wa.w, wb.x, wb.y, wb.z, wb.w};
    unsigned hv[4], lv[4];
    #pragma unroll
    for (int i = 0; i < 4; ++i) {
      unsigned short h0 = f2bf(f[2 * i]), h1 = f2bf(f[2 * i + 1]);
      unsigned short l0 = f2bf(f[2 * i] - bf2f(h0));
      unsigned short l1 = f2bf(f[2 * i + 1] - bf2f(h1));
      hv[i] = (unsigned)h0 | ((unsigned)h1 << 16);
      lv[i] = (unsigned)l0 | ((unsigned)l1 << 16);
    }
    const int swz = (q & 7) << 4;
    *(uint4*)(Wlds + q * 2048 + ((ch * 16) ^ swz)) =
        make_uint4(hv[0], hv[1], hv[2], hv[3]);
    *(uint4*)(Wlds + q * 2048 + ((1024 + ch * 16) ^ swz)) =
        make_uint4(lv[0], lv[1], lv[2], lv[3]);
    const int n2 = 8 + (tid >> 6);
    uint4 z4 = make_uint4(0, 0, 0, 0);
    *(uint4*)(Wlds + n2 * 2048 + ch * 32) = z4;
    *(uint4*)(Wlds + n2 * 2048 + ch * 32 + 16) = z4;
  }
  __syncthreads();

  // ================ G1: encode GEMM (waves 0,1) ============================
  if (w < 2) {
    const int rt = w;
    const float* xr = x + (size_t)(rowbase + rt * 16 + cl) * 512;
    f32x4 ea = (f32x4){0.f, 0.f, 0.f, 0.f};
    const int swz = (cl & 7) << 4;
    #pragma unroll
    for (int kb = 0; kb < 16; ++kb) {
      float4 xa = *(const float4*)(xr + kb * 32 + kg * 8);
      float4 xb = *(const float4*)(xr + kb * 32 + kg * 8 + 4);
      float f[8] = {xa.x, xa.y, xa.z, xa.w, xb.x, xb.y, xb.z, xb.w};
      bf16x8 hi8, lo8;
      #pragma unroll
      for (int i = 0; i < 8; ++i) {
        unsigned short h = f2bf(f[i]);
        hi8[i] = (short)h;
        lo8[i] = (short)f2bf(f[i] - bf2f(h));
      }
      bf16x8 bhi = *(const bf16x8*)(Wlds + cl * 2048 +
                                    ((kg * 16 + kb * 64) ^ swz));
      bf16x8 blo = *(const bf16x8*)(Wlds + cl * 2048 +
                                    ((1024 + kg * 16 + kb * 64) ^ swz));
      ea = __builtin_amdgcn_mfma_f32_16x16x32_bf16(hi8, bhi, ea, 0, 0, 0);
      ea = __builtin_amdgcn_mfma_f32_16x16x32_bf16(lo8, blo, ea, 0, 0, 0);
    }
    if (cl < 8) {
      #pragma unroll
      for (int jr = 0; jr < 4; ++jr) {
        float acc = ea[jr];
        float e  = __expf(2.f * acc);
        float th = 1.f - __fdividef(2.f, e + 1.f);  // tanh
        float h  = 1.57079632679489662f * th;       // (pi/2)*tanh
        cs_lds[rt * 16 + kg * 4 + jr][cl] = make_float2(__cosf(h), __sinf(h));
      }
    }
  }
  __syncthreads();

  // ================ psi assembly: 16 amps per thread =======================
  {
    const int row = tid >> 4;
    const int seg = tid & 15;
    float2 g0 = cs_lds[row][0], g1 = cs_lds[row][1];
    float2 g2 = cs_lds[row][2], g3 = cs_lds[row][3];
    float2 g4 = cs_lds[row][4], g5 = cs_lds[row][5];
    float2 g6 = cs_lds[row][6], g7 = cs_lds[row][7];
    float pre = ((seg & 8) ? g0.y : g0.x) * ((seg & 4) ? g1.y : g1.x) *
                ((seg & 2) ? g2.y : g2.x) * ((seg & 1) ? g3.y : g3.x);
    float p4[2], p5[4], p6[8], p7[16];
    p4[0] = pre * g4.x; p4[1] = pre * g4.y;
    #pragma unroll
    for (int a = 0; a < 2; ++a) {
      p5[a * 2]     = p4[a] * g5.x;
      p5[a * 2 + 1] = p4[a] * g5.y;
    }
    #pragma unroll
    for (int a = 0; a < 4; ++a) {
      p6[a * 2]     = p5[a] * g6.x;
      p6[a * 2 + 1] = p5[a] * g6.y;
    }
    #pragma unroll
    for (int a = 0; a < 8; ++a) {
      p7[a * 2]     = p6[a] * g7.x;
      p7[a * 2 + 1] = p6[a] * g7.y;
    }
    unsigned u[8];
    #pragma unroll
    for (int i = 0; i < 8; ++i)
      u[i] = (unsigned)f2bf(p7[2 * i]) | ((unsigned)f2bf(p7[2 * i + 1]) << 16);
    const int swz = (row & 7) << 4;
    *(uint4*)(psi_lds + row * 512 + ((seg * 32) ^ swz)) =
        make_uint4(u[0], u[1], u[2], u[3]);
    *(uint4*)(psi_lds + row * 512 + ((seg * 32 + 16) ^ swz)) =
        make_uint4(u[4], u[5], u[6], u[7]);
  }
  __syncthreads();

  // ================ wait for U; self-cleaning control words ================
  if (tid < 32) {
    while (__hip_atomic_load(&ctrl[tid], __ATOMIC_ACQUIRE,
                             __HIP_MEMORY_SCOPE_AGENT) != MAGIC)
      __builtin_amdgcn_s_sleep(2);
  }
  __syncthreads();
  if (tid == 0) {
    unsigned old = atomicAdd(&ctrl[32], 1u);
    if (old == 255u || old == 0xAAAAAAAAu + 255u) {  // last block (handles poison)
      #pragma unroll
      for (int i = 0; i < 33; ++i)
        __hip_atomic_store(&ctrl[i], 0u, __ATOMIC_RELEASE,
                           __HIP_MEMORY_SCOPE_AGENT);
    }
  }

  // ================ G2: main GEMM (wave -> 64 output cols) =================
  const int wcol = w * 64;

  bf16x8 Af[2][8];
  #pragma unroll
  for (int rt = 0; rt < 2; ++rt)
    #pragma unroll
    for (int kb = 0; kb < 8; ++kb) {
      int row = rt * 16 + cl;
      int byte = row * 512 + ((kg * 16 + kb * 64) ^ ((row & 7) << 4));
      Af[rt][kb] = *(const bf16x8*)(psi_lds + byte);
    }

  f32x4 acc2[2][4];
  #pragma unroll
  for (int rt = 0; rt < 2; ++rt)
    #pragma unroll
    for (int ct = 0; ct < 4; ++ct) acc2[rt][ct] = (f32x4){0.f, 0.f, 0.f, 0.f};

  const short* Bts = (const short*)Bt;
  #pragma unroll
  for (int kb = 0; kb < 8; ++kb) {
    #pragma unroll
    for (int ct = 0; ct < 4; ++ct) {
      bf16x8 bf = *(const bf16x8*)(Bts +
          (size_t)(wcol + ct * 16 + cl) * 256 + kg * 8 + kb * 32);
      acc2[0][ct] = __builtin_amdgcn_mfma_f32_16x16x32_bf16(Af[0][kb], bf,
                                                            acc2[0][ct], 0, 0, 0);
      acc2[1][ct] = __builtin_amdgcn_mfma_f32_16x16x32_bf16(Af[1][kb], bf,
                                                            acc2[1][ct], 0, 0, 0);
    }
  }

  // ---- epilogue: P = re^2+im^2 ; z_q += sign*P ----------------------------
  float zacc[2][4][4];
  #pragma unroll
  for (int rt = 0; rt < 2; ++rt)
    #pragma unroll
    for (int u = 0; u < 4; ++u)
      #pragma unroll
      for (int jr = 0; jr < 4; ++jr) zacc[rt][u][jr] = 0.f;

  #pragma unroll
  for (int ct = 0; ct < 4; ++ct) {
    int n = wcol + ct * 16 + cl;
    int i = n >> 1;
    int ib = (lane & 1) ? (i & 15) : (i >> 4);
    float s[4];
    #pragma unroll
    for (int u = 0; u < 4; ++u)
      s[u] = ((ib >> (3 - u)) & 1) ? -1.f : 1.f;
    #pragma unroll
    for (int rt = 0; rt < 2; ++rt) {
      #pragma unroll
      for (int jr = 0; jr < 4; ++jr) {
        float v = acc2[rt][ct][jr];
        v = v * v;
        float P = v + __shfl_xor(v, 1, 64);
        #pragma unroll
        for (int u = 0; u < 4; ++u)
          zacc[rt][u][jr] = fmaf(s[u], P, zacc[rt][u][jr]);
      }
    }
  }

  #pragma unroll
  for (int m = 2; m <= 8; m <<= 1)
    #pragma unroll
    for (int rt = 0; rt < 2; ++rt)
      #pragma unroll
      for (int u = 0; u < 4; ++u)
        #pragma unroll
        for (int jr = 0; jr < 4; ++jr)
          zacc[rt][u][jr] += __shfl_xor(zacc[rt][u][jr], m, 64);

  if (cl <= 1) {
    #pragma unroll
    for (int rt = 0; rt < 2; ++rt)
      #pragma unroll
      for (int u = 0; u < 4; ++u)
        #pragma unroll
        for (int jr = 0; jr < 4; ++jr)
          z_lds[w][rt * 16 + kg * 4 + jr][(lane & 1) * 4 + u] = zacc[rt][u][jr];
  }
  __syncthreads();

  if (tid < 256) {  // sum the 8 wave partials
    int r = tid >> 3, q = tid & 7;
    float s = 0.f;
    #pragma unroll
    for (int wv = 0; wv < 8; ++wv) s += z_lds[wv][r][q];
    z_final[r][q] = s;
  }
  __syncthreads();

  // ---- out = z @ W_out^T : thread t -> col t ------------------------------
  float4 wa = *(const float4*)(W_out + (size_t)tid * 8);
  float4 wb = *(const float4*)(W_out + (size_t)tid * 8 + 4);
  #pragma unroll 4
  for (int r = 0; r < 32; ++r) {
    float4 z0 = *(const float4*)&z_final[r][0];
    float4 z1 = *(const float4*)&z_final[r][4];
    float d = wa.x * z0.x + wa.y * z0.y + wa.z * z0.z + wa.w * z0.w +
              wb.x * z1.x + wb.y * z1.y + wb.z * z1.z + wb.w * z1.w;
    out[(size_t)(rowbase + r) * 512 + tid] = d;
  }
}

extern "C" void kernel_launch(void* const* d_in, const int* in_sizes, int n_in,
                              void* d_out, int out_size, void* d_ws, size_t ws_size,
                              hipStream_t stream) {
  const float* x     = (const float*)d_in[0];  // (B, 512)
  const float* W_in  = (const float*)d_in[1];  // (8, 512)
  const float* W_out = (const float*)d_in[2];  // (512, 8)
  const float* theta = (const float*)d_in[3];  // (4, 8, 3)
  float* out = (float*)d_out;

  const int B = in_sizes[0] / 512;  // 8192
  __hip_bfloat16* Bt = (__hip_bfloat16*)d_ws;            // 512*256 bf16
  unsigned* ctrl = (unsigned*)((char*)d_ws + 262144);    // 32 markers + done

  hipLaunchKernelGGL(mono_kernel, dim3(B / 32), dim3(512), 0, stream,
                     x, W_in, W_out, theta, Bt, ctrl, out);
}

// Round 8
// 34.044 us; speedup vs baseline: 2.5431x; 2.5431x over previous
//
#include <hip/hip_runtime.h>
#include <hip/hip_bf16.h>
#include <math.h>

// ---------------------------------------------------------------------------
// HybridQuantumLinear via fixed-unitary GEMM (R2 arrangement + padded strides).
//   k01: blocks 0..63 build U (256x256 fixed unitary) -> Bt[512][BTS] bf16
//        (row n = 2i+c re/im of output amp i, col j = input amp);
//        blocks 64.. encode: enc=tanh(x@W_in^T)*pi -> psi_in (REAL product
//        state) to global, rows padded to PSIS shorts. One wave per batch row.
//   k2:  256 blocks x 4 waves; block = 32 batch rows; wave = 128 output cols.
//        psi_out = psi_in @ Bt^T via MFMA 16x16x32 (K=256, N=512);
//        P_i = re^2+im^2 ; z_q = sum sign_q(i) P_i ; out = z @ W_out^T.
// Strides padded to 576 B (9 cache lines) to avoid L2 channel camping that
// a 512 B power-of-2 stride causes on 16-lane strided fragment loads.
// Amp index i: bit(7-q) = qubit q. In U-build, i = lane*4 + k.
// ---------------------------------------------------------------------------

#define BTS 288   // Bt row stride in shorts (576 B)
#define PSIS 288  // psi row stride in shorts (576 B)

typedef __attribute__((ext_vector_type(8))) short bf16x8;
typedef __attribute__((ext_vector_type(4))) float f32x4;

__device__ __forceinline__ float2 shfl_xor_f2(float2 v, int m) {
  float2 r;
  r.x = __shfl_xor(v.x, m, 64);
  r.y = __shfl_xor(v.y, m, 64);
  return r;
}
// acc += u*v (complex)
__device__ __forceinline__ float2 cfma(float2 u, float2 v, float2 acc) {
  acc.x = fmaf(u.x, v.x, fmaf(-u.y, v.y, acc.x));
  acc.y = fmaf(u.x, v.y, fmaf(u.y, v.x, acc.y));
  return acc;
}

// general 2x2 gate on qubit q
__device__ __forceinline__ void apply_gate(float2 (&a)[4], int q, float2 u00,
                                           float2 u01, float2 u10, float2 u11,
                                           int lane) {
  const float2 z0 = make_float2(0.f, 0.f);
  if (q == 7) {  // amp bit 0: pairs (0,1),(2,3)
    float2 n0 = cfma(u00, a[0], cfma(u01, a[1], z0));
    float2 n1 = cfma(u10, a[0], cfma(u11, a[1], z0));
    float2 n2 = cfma(u00, a[2], cfma(u01, a[3], z0));
    float2 n3 = cfma(u10, a[2], cfma(u11, a[3], z0));
    a[0] = n0; a[1] = n1; a[2] = n2; a[3] = n3;
  } else if (q == 6) {  // amp bit 1: pairs (0,2),(1,3)
    float2 n0 = cfma(u00, a[0], cfma(u01, a[2], z0));
    float2 n2 = cfma(u10, a[0], cfma(u11, a[2], z0));
    float2 n1 = cfma(u00, a[1], cfma(u01, a[3], z0));
    float2 n3 = cfma(u10, a[1], cfma(u11, a[3], z0));
    a[0] = n0; a[1] = n1; a[2] = n2; a[3] = n3;
  } else {  // lane bit (5-q)
    int m = 1 << (5 - q);
    bool b = (lane >> (5 - q)) & 1;
    float2 ca = b ? u11 : u00;
    float2 cp = b ? u10 : u01;
    #pragma unroll
    for (int k = 0; k < 4; ++k) {
      float2 p = shfl_xor_f2(a[k], m);
      a[k] = cfma(ca, a[k], cfma(cp, p, z0));
    }
  }
}

// CNOT(control q, target q+1)
__device__ __forceinline__ void apply_cnot(float2 (&a)[4], int q, int lane) {
  if (q <= 4) {
    int m = 1 << (4 - q);
    bool ctrl = (lane >> (5 - q)) & 1;
    #pragma unroll
    for (int k = 0; k < 4; ++k) {
      float2 p = shfl_xor_f2(a[k], m);
      a[k].x = ctrl ? p.x : a[k].x;
      a[k].y = ctrl ? p.y : a[k].y;
    }
  } else if (q == 5) {  // control = lane bit 0, target = k bit 1
    bool ct = lane & 1;
    float2 n0 = ct ? a[2] : a[0];
    float2 n1 = ct ? a[3] : a[1];
    float2 n2 = ct ? a[0] : a[2];
    float2 n3 = ct ? a[1] : a[3];
    a[0] = n0; a[1] = n1; a[2] = n2; a[3] = n3;
  } else {  // q == 6: control = k bit 1, target = k bit 0
    float2 t = a[2]; a[2] = a[3]; a[3] = t;
  }
}

__global__ __launch_bounds__(256) void k01_kernel(
    const float* __restrict__ x, const float* __restrict__ W_in,
    const float* __restrict__ theta, __hip_bfloat16* __restrict__ Bt,
    __hip_bfloat16* __restrict__ psi, int B) {
  __shared__ float mats[32 * 8];
  const int tid = threadIdx.x;
  const int lane = tid & 63;

  if (blockIdx.x < 64) {
    // ---------------- U-build: fused gate matrices, then basis-state sim ----
    if (tid < 32) {
      int l = tid >> 3, q = tid & 7;
      const float* th = theta + (l * 8 + q) * 3;
      float h1 = 0.5f * th[0], h2 = 0.5f * th[1], h3 = 0.5f * th[2];
      float c1 = cosf(h1), s1 = sinf(h1);
      float c2 = cosf(h2), s2 = sinf(h2);
      float c3 = cosf(h3), s3 = sinf(h3);
      // M = RY*RX
      float m00r = c2 * c1, m00i = s2 * s1;
      float m01r = -s2 * c1, m01i = -c2 * s1;
      float m10r = s2 * c1, m10i = -c2 * s1;
      float m11r = c1 * c2, m11i = -s1 * s2;
      // U = RZ*M: row0 *= (c3 - i s3), row1 *= (c3 + i s3)
      float* o = &mats[tid * 8];
      o[0] = c3 * m00r + s3 * m00i;  o[1] = c3 * m00i - s3 * m00r;
      o[2] = c3 * m01r + s3 * m01i;  o[3] = c3 * m01i - s3 * m01r;
      o[4] = c3 * m10r - s3 * m10i;  o[5] = c3 * m10i + s3 * m10r;
      o[6] = c3 * m11r - s3 * m11i;  o[7] = c3 * m11i + s3 * m11r;
    }
    __syncthreads();

    const int j = blockIdx.x * 4 + (tid >> 6);  // basis column 0..255
    float2 a[4];
    #pragma unroll
    for (int k = 0; k < 4; ++k)
      a[k] = make_float2((lane * 4 + k == j) ? 1.f : 0.f, 0.f);

    #pragma unroll
    for (int l = 0; l < 4; ++l) {
      #pragma unroll
      for (int q = 0; q < 8; ++q) {
        const float* m = &mats[(l * 8 + q) * 8];
        float2 u00 = make_float2(m[0], m[1]);
        float2 u01 = make_float2(m[2], m[3]);
        float2 u10 = make_float2(m[4], m[5]);
        float2 u11 = make_float2(m[6], m[7]);
        apply_gate(a, q, u00, u01, u10, u11, lane);
      }
      #pragma unroll
      for (int i = (l & 1); i < 7; i += 2) apply_cnot(a, i, lane);
    }
    // Bt[n][j], n = 2i + c, i = lane*4 + k  (row-major 512 x BTS)
    #pragma unroll
    for (int k = 0; k < 4; ++k) {
      int n0 = (lane * 4 + k) * 2;
      Bt[n0 * BTS + j]       = __float2bfloat16(a[k].x);
      Bt[(n0 + 1) * BTS + j] = __float2bfloat16(a[k].y);
    }
    return;
  }

  // ---------------- encoding + psi_in ----------------
  const int b = (int)(blockIdx.x - 64) * 4 + (tid >> 6);
  if (b >= B) return;

  float xv[8];
  #pragma unroll
  for (int j = 0; j < 8; ++j) xv[j] = x[b * 512 + j * 64 + lane];

  float acc[8];
  #pragma unroll
  for (int q = 0; q < 8; ++q) {
    float s = 0.f;
    #pragma unroll
    for (int j = 0; j < 8; ++j)
      s = fmaf(xv[j], W_in[q * 512 + j * 64 + lane], s);
    acc[q] = s;
  }
  #pragma unroll
  for (int m = 1; m < 64; m <<= 1) {
    #pragma unroll
    for (int q = 0; q < 8; ++q) acc[q] += __shfl_xor(acc[q], m, 64);
  }

  float cq[8], sq[8];
  #pragma unroll
  for (int q = 0; q < 8; ++q) {
    float e  = __expf(2.f * acc[q]);
    float th = 1.f - __fdividef(2.f, e + 1.f);  // tanh
    float h  = 1.57079632679489662f * th;       // (pi/2) * tanh
    cq[q] = __cosf(h);
    sq[q] = __sinf(h);
  }

  float base = 1.f;
  #pragma unroll
  for (int q = 0; q < 6; ++q)
    base *= ((lane >> (5 - q)) & 1) ? sq[q] : cq[q];

  float a0 = base * cq[6] * cq[7];
  float a1 = base * cq[6] * sq[7];
  float a2 = base * sq[6] * cq[7];
  float a3 = base * sq[6] * sq[7];

  __hip_bfloat16 h4[4] = {__float2bfloat16(a0), __float2bfloat16(a1),
                          __float2bfloat16(a2), __float2bfloat16(a3)};
  uint2 pk = *reinterpret_cast<uint2*>(h4);
  *reinterpret_cast<uint2*>(psi + (size_t)b * PSIS + lane * 4) = pk;
}

__global__ __launch_bounds__(256, 1) void k2_kernel(
    const __hip_bfloat16* __restrict__ psi, const __hip_bfloat16* __restrict__ Bt,
    const float* __restrict__ W_out, float* __restrict__ out) {
  __shared__ float z_lds[4][32][8];
  __shared__ float z_final[32][8];
  const int tid = threadIdx.x;
  const int lane = tid & 63;
  const int w = tid >> 6;
  const int rowbase = blockIdx.x * 32;
  const int cl = lane & 15;  // col-lane / A-row lane
  const int kg = lane >> 4;  // k-group

  const short* psis = (const short*)psi;
  const short* Bts  = (const short*)Bt;

  // A fragments: A[row][k] = psi_in, row = rowbase + rt*16 + cl, k contiguous
  bf16x8 Af[2][8];
  #pragma unroll
  for (int rt = 0; rt < 2; ++rt)
    #pragma unroll
    for (int kb = 0; kb < 8; ++kb)
      Af[rt][kb] = *(const bf16x8*)(psis +
          (size_t)(rowbase + rt * 16 + cl) * PSIS + kb * 32 + kg * 8);

  const int wcol = w * 128;
  f32x4 acc[2][8];
  #pragma unroll
  for (int rt = 0; rt < 2; ++rt)
    #pragma unroll
    for (int ct = 0; ct < 8; ++ct) acc[rt][ct] = (f32x4){0.f, 0.f, 0.f, 0.f};

  #pragma unroll
  for (int ct = 0; ct < 8; ++ct) {
    const short* bp = Bts + (size_t)(wcol + ct * 16 + cl) * BTS + kg * 8;
    bf16x8 Bf[8];
    #pragma unroll
    for (int kb = 0; kb < 8; ++kb) Bf[kb] = *(const bf16x8*)(bp + kb * 32);
    #pragma unroll
    for (int kb = 0; kb < 8; ++kb) {
      acc[0][ct] = __builtin_amdgcn_mfma_f32_16x16x32_bf16(Af[0][kb], Bf[kb],
                                                           acc[0][ct], 0, 0, 0);
      acc[1][ct] = __builtin_amdgcn_mfma_f32_16x16x32_bf16(Af[1][kb], Bf[kb],
                                                           acc[1][ct], 0, 0, 0);
    }
  }

  // ---- epilogue: P_i = re^2+im^2, z_q += sign * P. Even lanes do q0..3,
  // odd lanes q4..7 (partner lane holds the other component of the same i).
  float zacc[2][4][4];
  #pragma unroll
  for (int rt = 0; rt < 2; ++rt)
    #pragma unroll
    for (int u = 0; u < 4; ++u)
      #pragma unroll
      for (int jr = 0; jr < 4; ++jr) zacc[rt][u][jr] = 0.f;

  #pragma unroll
  for (int ct = 0; ct < 8; ++ct) {
    int n = wcol + ct * 16 + cl;
    int i = n >> 1;
    int ib = (lane & 1) ? (i & 15) : (i >> 4);
    float s[4];
    #pragma unroll
    for (int u = 0; u < 4; ++u)
      s[u] = ((ib >> (3 - u)) & 1) ? -1.f : 1.f;
    #pragma unroll
    for (int rt = 0; rt < 2; ++rt) {
      #pragma unroll
      for (int jr = 0; jr < 4; ++jr) {
        float v = acc[rt][ct][jr];
        v = v * v;
        float P = v + __shfl_xor(v, 1, 64);
        #pragma unroll
        for (int u = 0; u < 4; ++u)
          zacc[rt][u][jr] = fmaf(s[u], P, zacc[rt][u][jr]);
      }
    }
  }

  // reduce over same-parity col-lanes (lane bits 1..3)
  #pragma unroll
  for (int m = 2; m <= 8; m <<= 1)
    #pragma unroll
    for (int rt = 0; rt < 2; ++rt)
      #pragma unroll
      for (int u = 0; u < 4; ++u)
        #pragma unroll
        for (int jr = 0; jr < 4; ++jr)
          zacc[rt][u][jr] += __shfl_xor(zacc[rt][u][jr], m, 64);

  if (cl <= 1) {
    #pragma unroll
    for (int rt = 0; rt < 2; ++rt)
      #pragma unroll
      for (int u = 0; u < 4; ++u)
        #pragma unroll
        for (int jr = 0; jr < 4; ++jr)
          z_lds[w][rt * 16 + kg * 4 + jr][(lane & 1) * 4 + u] = zacc[rt][u][jr];
  }
  __syncthreads();

  {  // sum the 4 wave-partials
    int r = tid >> 3, q = tid & 7;
    z_final[r][q] = z_lds[0][r][q] + z_lds[1][r][q] + z_lds[2][r][q] +
                    z_lds[3][r][q];
  }
  __syncthreads();

  // ---- out = z @ W_out^T ----
  const int o0 = tid, o1 = 256 + tid;
  float4 wa0 = *(const float4*)(W_out + o0 * 8);
  float4 wb0 = *(const float4*)(W_out + o0 * 8 + 4);
  float4 wa1 = *(const float4*)(W_out + o1 * 8);
  float4 wb1 = *(const float4*)(W_out + o1 * 8 + 4);
  #pragma unroll 4
  for (int r = 0; r < 32; ++r) {
    float4 z0 = *(const float4*)&z_final[r][0];
    float4 z1 = *(const float4*)&z_final[r][4];
    float d0 = wa0.x * z0.x + wa0.y * z0.y + wa0.z * z0.z + wa0.w * z0.w +
               wb0.x * z1.x + wb0.y * z1.y + wb0.z * z1.z + wb0.w * z1.w;
    float d1 = wa1.x * z0.x + wa1.y * z0.y + wa1.z * z0.z + wa1.w * z0.w +
               wb1.x * z1.x + wb1.y * z1.y + wb1.z * z1.z + wb1.w * z1.w;
    out[(size_t)(rowbase + r) * 512 + o0] = d0;
    out[(size_t)(rowbase + r) * 512 + o1] = d1;
  }
}

extern "C" void kernel_launch(void* const* d_in, const int* in_sizes, int n_in,
                              void* d_out, int out_size, void* d_ws, size_t ws_size,
                              hipStream_t stream) {
  const float* x     = (const float*)d_in[0];  // (B, 512)
  const float* W_in  = (const float*)d_in[1];  // (8, 512)
  const float* W_out = (const float*)d_in[2];  // (512, 8)
  const float* theta = (const float*)d_in[3];  // (4, 8, 3)
  float* out = (float*)d_out;

  const int B = in_sizes[0] / 512;  // 8192
  const size_t btBytes = (size_t)512 * BTS * sizeof(__hip_bfloat16);

  __hip_bfloat16* Bt  = (__hip_bfloat16*)d_ws;
  __hip_bfloat16* psi = (__hip_bfloat16*)((char*)d_ws + btBytes);

  hipLaunchKernelGGL(k01_kernel, dim3(64 + B / 4), dim3(256), 0, stream,
                     x, W_in, theta, Bt, psi, B);
  hipLaunchKernelGGL(k2_kernel, dim3(B / 32), dim3(256), 0, stream,
                     psi, Bt, W_out, out);
}